// Round 1
// baseline (958.121 us; speedup 1.0000x reference)
//
#include <hip/hip_runtime.h>
#include <math.h>

// FuzzyAttention: V = softmax(scale * (S + 0.5*sigmoid(S)) with causal mask) @ values
// S = Q K^T, scale = 1/sqrt(64). Shapes: Q,K,V,out = [B=2, L=2048, H=16, E=64] f32.
// Causal mask is the fixed triu(k=1) mask -> computed analytically, mask input ignored.

constexpr int Bc  = 2;
constexpr int Lc  = 2048;
constexpr int Hc  = 16;
constexpr int Ec  = 64;
constexpr int BM  = 64;              // q rows per tile
constexpr int BN  = 64;              // kv rows per tile
constexpr int NQT = Lc / BM;         // 32 q-tiles
constexpr int ROW_STRIDE = Hc * Ec;  // 1024 floats between consecutive l
constexpr float FUZZ_DELTA = 0.5f;
constexpr float SM_SCALE   = 0.125f; // 1/sqrt(64)

__global__ __launch_bounds__(256, 2)
void fuzzy_attn_f32(const float* __restrict__ Qp,
                    const float* __restrict__ Kp,
                    const float* __restrict__ Vp,
                    float* __restrict__ Op) {
    __shared__ float kt[BN][Ec];       // K tile  (hot reads are wave-broadcast)
    __shared__ float vt[BN][Ec];       // V tile  (hot reads are wave-broadcast)
    __shared__ float pt[BM][BN + 1];   // score tile, +1 pad -> (m+n)%32 banks

    const int tid = threadIdx.x;
    const int m   = tid & 63;          // query row within tile
    const int q4  = tid >> 6;          // wave id: owns n-slice & d-slice [q4*16, q4*16+16)
    const int bh  = blockIdx.y;
    const int b   = bh >> 4;           // H = 16
    const int h   = bh & 15;

    const long long batch_stride = (long long)Lc * ROW_STRIDE;
    const float* Qb = Qp + (long long)b * batch_stride + h * Ec;
    const float* Kb = Kp + (long long)b * batch_stride + h * Ec;
    const float* Vb = Vp + (long long)b * batch_stride + h * Ec;
    float*       Ob = Op + (long long)b * batch_stride + h * Ec;

    // Pair q-tiles (x, NQT-1-x): (x+1)+(NQT-x) = 33 KV iterations per block -> balanced.
    const int qts[2] = { (int)blockIdx.x, NQT - 1 - (int)blockIdx.x };

    const int sn = tid >> 2;   // staging: row this thread loads
    const int sc = tid & 3;    // staging: 16-float chunk within row

    for (int qi = 0; qi < 2; ++qi) {
        const int qt = qts[qi];

        // ---- Q row -> 64 VGPRs ----
        float4 qreg[16];
        const float4* qrow =
            reinterpret_cast<const float4*>(Qb + (long long)(qt * BM + m) * ROW_STRIDE);
        #pragma unroll
        for (int i = 0; i < 16; ++i) qreg[i] = qrow[i];

        float mrun = -INFINITY;
        float lrun = 0.f;
        float oacc[16];
        #pragma unroll
        for (int i = 0; i < 16; ++i) oacc[i] = 0.f;

        for (int st = 0; st <= qt; ++st) {
            // ---- stage K/V tile (each thread: 4x float4 of one row chunk) ----
            {
                const float* krow = Kb + (long long)(st * BN + sn) * ROW_STRIDE + sc * 16;
                const float* vrow = Vb + (long long)(st * BN + sn) * ROW_STRIDE + sc * 16;
                const float4* ksrc = reinterpret_cast<const float4*>(krow);
                const float4* vsrc = reinterpret_cast<const float4*>(vrow);
                float4* kdst = reinterpret_cast<float4*>(&kt[sn][sc * 16]);
                float4* vdst = reinterpret_cast<float4*>(&vt[sn][sc * 16]);
                #pragma unroll
                for (int i = 0; i < 4; ++i) { kdst[i] = ksrc[i]; vdst[i] = vsrc[i]; }
            }
            __syncthreads();

            // ---- scores for this wave's n-slice ----
            const bool diag = (st == qt);
            #pragma unroll
            for (int jn = 0; jn < 16; ++jn) {
                const int nn = q4 * 16 + jn;
                float s = 0.f;
                #pragma unroll
                for (int i = 0; i < 16; ++i) {
                    const float4 kv = *reinterpret_cast<const float4*>(&kt[nn][i * 4]);
                    s = fmaf(qreg[i].x, kv.x, s);
                    s = fmaf(qreg[i].y, kv.y, s);
                    s = fmaf(qreg[i].z, kv.z, s);
                    s = fmaf(qreg[i].w, kv.w, s);
                }
                // fuzzy: (s + delta*sigmoid(s)) * scale, then causal mask
                float f = (s + FUZZ_DELTA / (1.f + __expf(-s))) * SM_SCALE;
                if (diag && nn > m) f = -INFINITY;
                pt[m][nn] = f;
            }
            __syncthreads();

            // ---- online softmax + PV for row m, d-slice q4 ----
            float tmax = -INFINITY;
            #pragma unroll 16
            for (int nn = 0; nn < BN; ++nn) tmax = fmaxf(tmax, pt[m][nn]);
            const float mnew  = fmaxf(mrun, tmax);
            const float alpha = __expf(mrun - mnew);   // first tile: exp(-inf)=0
            mrun = mnew;
            lrun *= alpha;
            #pragma unroll
            for (int i = 0; i < 16; ++i) oacc[i] *= alpha;

            #pragma unroll 4
            for (int nn = 0; nn < BN; ++nn) {
                const float p = __expf(pt[m][nn] - mnew);  // masked: exp(-inf)=0
                lrun += p;
                const float4 v0 = *reinterpret_cast<const float4*>(&vt[nn][q4 * 16 + 0]);
                const float4 v1 = *reinterpret_cast<const float4*>(&vt[nn][q4 * 16 + 4]);
                const float4 v2 = *reinterpret_cast<const float4*>(&vt[nn][q4 * 16 + 8]);
                const float4 v3 = *reinterpret_cast<const float4*>(&vt[nn][q4 * 16 + 12]);
                oacc[0]  = fmaf(p, v0.x, oacc[0]);
                oacc[1]  = fmaf(p, v0.y, oacc[1]);
                oacc[2]  = fmaf(p, v0.z, oacc[2]);
                oacc[3]  = fmaf(p, v0.w, oacc[3]);
                oacc[4]  = fmaf(p, v1.x, oacc[4]);
                oacc[5]  = fmaf(p, v1.y, oacc[5]);
                oacc[6]  = fmaf(p, v1.z, oacc[6]);
                oacc[7]  = fmaf(p, v1.w, oacc[7]);
                oacc[8]  = fmaf(p, v2.x, oacc[8]);
                oacc[9]  = fmaf(p, v2.y, oacc[9]);
                oacc[10] = fmaf(p, v2.z, oacc[10]);
                oacc[11] = fmaf(p, v2.w, oacc[11]);
                oacc[12] = fmaf(p, v3.x, oacc[12]);
                oacc[13] = fmaf(p, v3.y, oacc[13]);
                oacc[14] = fmaf(p, v3.z, oacc[14]);
                oacc[15] = fmaf(p, v3.w, oacc[15]);
            }
            __syncthreads();   // protect kt/vt/pt before next stage
        }

        // ---- epilogue: normalize + write this row's d-slice ----
        const float inv = 1.f / lrun;   // lrun > 0: diagonal always has s=l valid
        float* orow = Ob + (long long)(qt * BM + m) * ROW_STRIDE + q4 * 16;
        float4 o0 = make_float4(oacc[0] * inv,  oacc[1] * inv,  oacc[2] * inv,  oacc[3] * inv);
        float4 o1 = make_float4(oacc[4] * inv,  oacc[5] * inv,  oacc[6] * inv,  oacc[7] * inv);
        float4 o2 = make_float4(oacc[8] * inv,  oacc[9] * inv,  oacc[10] * inv, oacc[11] * inv);
        float4 o3 = make_float4(oacc[12] * inv, oacc[13] * inv, oacc[14] * inv, oacc[15] * inv);
        reinterpret_cast<float4*>(orow)[0] = o0;
        reinterpret_cast<float4*>(orow)[1] = o1;
        reinterpret_cast<float4*>(orow)[2] = o2;
        reinterpret_cast<float4*>(orow)[3] = o3;
    }
}

extern "C" void kernel_launch(void* const* d_in, const int* in_sizes, int n_in,
                              void* d_out, int out_size, void* d_ws, size_t ws_size,
                              hipStream_t stream) {
    (void)in_sizes; (void)n_in; (void)d_ws; (void)ws_size; (void)out_size;
    const float* Q = (const float*)d_in[0];
    const float* K = (const float*)d_in[1];
    const float* V = (const float*)d_in[2];
    // d_in[3] = causal mask (fixed triu k=1) -> handled analytically in-kernel.
    float* O = (float*)d_out;

    dim3 grid(NQT / 2, Bc * Hc);   // 16 x 32 = 512 blocks, 33 KV-iters each
    fuzzy_attn_f32<<<grid, 256, 0, stream>>>(Q, K, V, O);
}